// Round 7
// baseline (493.984 us; speedup 1.0000x reference)
//
#include <hip/hip_runtime.h>
#include <hip/hip_bf16.h>
#include <cstdint>
#include <cstddef>

// DecoderLayer: S=1024 B=4 D=1024 H=16 HD=64 DFF=4096, all f32 in/out.
// R13: BK 64 -> 32 in gemm_qkv/gemm_nt (tile 128x128, dbuf+PIN kept).
// LDS 64 -> 32 KiB per block => blocks/CU cap 2 -> 5 (88 VGPR allows ~5
// waves/SIMD). Session insight: every schedule at 2 blocks/CU landed on the
// same ~480us plateau; the guide's working point for this structure is >=3
// blocks/CU (m114 cross-block overlap hides the barrier drain). Bonus: qkv's
// 1280 blocks = exactly 5x256 (zero tail); FFN/O-proj/crossK fully resident.
// Swizzle re-derived for 32-elem rows (write chunk (l&3)^((l>>3)&3), read
// slot quad^((l16>>1)&3); worst 2-way = free). attn/LN/cast unchanged.

typedef __bf16 bf16;
typedef __attribute__((ext_vector_type(8))) __bf16 bf16x8;
typedef __attribute__((ext_vector_type(4))) __bf16 bf16x4;
typedef __attribute__((ext_vector_type(4))) float f32x4;

#define SEQ   1024
#define BATCH 4
#define DMOD  1024
#define NHEAD 16
#define HDIM  64
#define NTOK  (SEQ*BATCH)
#define DFF   4096

#define GLD(gp, lp) __builtin_amdgcn_global_load_lds( \
    (__attribute__((address_space(1))) void*)(gp),    \
    (__attribute__((address_space(3))) void*)(lp), 16, 0, 0)

#define PIN() __builtin_amdgcn_sched_barrier(0)

static __device__ __forceinline__ void pipe_sync() {
  asm volatile("s_waitcnt vmcnt(0)" ::: "memory");
  __builtin_amdgcn_s_barrier();
  asm volatile("" ::: "memory");
}

// ---------------- batched f32 -> bf16 cast (24 uniform chunks) --------------
struct CastSeg { const float* src; bf16* dst; int n4; };
struct CastArgs { CastSeg seg[24]; };

__global__ __launch_bounds__(256) void cast_multi(CastArgs a) {
  CastSeg s = a.seg[blockIdx.y];
  int i = blockIdx.x * 256 + threadIdx.x;
  if (i < s.n4) {
    float4 v = ((const float4*)s.src)[i];
    bf16x4 o; o[0] = (bf16)v.x; o[1] = (bf16)v.y; o[2] = (bf16)v.z; o[3] = (bf16)v.w;
    ((bf16x4*)s.dst)[i] = o;
  }
}

// ---------------- merged QKV(self) + QV(cross) GEMM (BK=32) ----------------
// 1280 blocks (= exactly 5/CU x 256 CUs when resident): id<768 -> self
// (A=x0b, W=[wq;wk;wv], N=3072); else cross (A=encb, W=[wq;wv], N=2048).
// Q scaled by 0.125 (incl bias). V written transposed: VT[bh][hd][s].
__global__ __launch_bounds__(256) void gemm_qkv(
    const bf16* __restrict__ x0b, const bf16* __restrict__ encb,
    const bf16* __restrict__ Wqkv, const bf16* __restrict__ Wqv,
    const float* __restrict__ sbq, const float* __restrict__ sbk,
    const float* __restrict__ sbv,
    const float* __restrict__ cbq, const float* __restrict__ cbv,
    bf16* __restrict__ Qs, bf16* __restrict__ Ks, bf16* __restrict__ VTs,
    bf16* __restrict__ Qc, bf16* __restrict__ VTc)
{
  __shared__ bf16 As[2][128 * 32];
  __shared__ bf16 Bs[2][128 * 32];
  const int tid  = threadIdx.x;
  const int wave = tid >> 6, lane = tid & 63;
  const int quad = lane >> 4, l16 = lane & 15;

  int id = blockIdx.x, seg, bx, by;
  const bf16 *A, *W;
  if (id < 768) {
    seg = 0; const int c = id & 7, q = id >> 3;
    by = c * 4 + (q & 3); bx = q >> 2;  // by fastest (L2 window), bx 0..23
    A = x0b; W = Wqkv;
  } else {
    id -= 768;
    seg = 1; const int c = id & 7, q = id >> 3;
    by = c * 4 + (q & 3); bx = q >> 2;  // bx 0..15
    A = encb; W = Wqv;
  }
  const int K = 1024;
  const int m0 = by * 128, n0 = bx * 128;
  const int wm = (wave >> 1) * 64, wn = (wave & 1) * 64;

  f32x4 acc[4][4] = {};
  const int srow4 = lane >> 2;                       // 0..15
  const int sgc = ((lane & 3) ^ ((lane >> 3) & 3)) * 8;  // swizzled src chunk
  const bf16* Ap = A + (size_t)(m0 + wave * 32 + srow4) * K + sgc;
  const bf16* Wp = W + (size_t)(n0 + wave * 32 + srow4) * K + sgc;
  const size_t rstep16 = (size_t)16 * K;
  const int woff = (wave * 32) * 32;
  const int g = (quad ^ ((l16 >> 1) & 3)) * 8;       // fragment-read slot

  auto stage = [&](bf16* AsD, bf16* BsD, int k0) {
    GLD(Ap + k0,           AsD + woff);
    GLD(Ap + rstep16 + k0, AsD + woff + 512);
    GLD(Wp + k0,           BsD + woff);
    GLD(Wp + rstep16 + k0, BsD + woff + 512);
  };
  auto compute = [&](const bf16* AsB, const bf16* BsB) {
    bf16x8 wf[4], tf[4];
#pragma unroll
    for (int i = 0; i < 4; ++i)
      wf[i] = *(const bf16x8*)(BsB + (wn + i * 16 + l16) * 32 + g);
#pragma unroll
    for (int i = 0; i < 4; ++i)
      tf[i] = *(const bf16x8*)(AsB + (wm + i * 16 + l16) * 32 + g);
#pragma unroll
    for (int mi = 0; mi < 4; ++mi)
#pragma unroll
      for (int ni = 0; ni < 4; ++ni)
        acc[mi][ni] = __builtin_amdgcn_mfma_f32_16x16x32_bf16(wf[mi], tf[ni], acc[mi][ni], 0, 0, 0);
  };

  stage(As[0], Bs[0], 0);
  pipe_sync();
  int k0 = 0;
  for (; k0 < K - 64; k0 += 64) {
    stage(As[1], Bs[1], k0 + 32);
    PIN();
    compute(As[0], Bs[0]);
    pipe_sync();
    stage(As[0], Bs[0], k0 + 64);
    PIN();
    compute(As[1], Bs[1]);
    pipe_sync();
  }
  stage(As[1], Bs[1], K - 32);
  PIN();
  compute(As[0], Bs[0]);
  pipe_sync();
  compute(As[1], Bs[1]);

  const int region = n0 >> 10;   // block-uniform: 0=Q, 1=K(self), last=V
  const bool isV = (seg == 0) ? (region == 2) : (region == 1);
#pragma unroll
  for (int ni = 0; ni < 4; ++ni) {
    const int i = m0 + wm + ni * 16 + l16;       // token (s*4+b)
#pragma unroll
    for (int mi = 0; mi < 4; ++mi) {
      const int gf = n0 + wn + mi * 16 + quad * 4;
      const int lf = gf & 1023;
      if (!isV) {
        if (region == 0) {   // Q (scaled)
          const float* bq = (seg == 0) ? sbq : cbq;
          const float4 bi = *(const float4*)(bq + lf);
          bf16* dst = ((seg == 0) ? Qs : Qc) + (size_t)i * 1024 + lf;
          bf16x4 o;
          o[0] = (bf16)((acc[mi][ni][0] + bi.x) * 0.125f);
          o[1] = (bf16)((acc[mi][ni][1] + bi.y) * 0.125f);
          o[2] = (bf16)((acc[mi][ni][2] + bi.z) * 0.125f);
          o[3] = (bf16)((acc[mi][ni][3] + bi.w) * 0.125f);
          *(bf16x4*)dst = o;
        } else {             // K (self only)
          const float4 bi = *(const float4*)(sbk + lf);
          bf16x4 o;
          o[0] = (bf16)(acc[mi][ni][0] + bi.x);
          o[1] = (bf16)(acc[mi][ni][1] + bi.y);
          o[2] = (bf16)(acc[mi][ni][2] + bi.z);
          o[3] = (bf16)(acc[mi][ni][3] + bi.w);
          *(bf16x4*)(Ks + (size_t)i * 1024 + lf) = o;
        }
      } else {               // V -> transposed VT[bh][hd][s]
        const float* bv = (seg == 0) ? sbv : cbv;
        const float4 bi = *(const float4*)(bv + lf);
        const int h = lf >> 6, hd = lf & 63;
        const int b = i & 3, s = i >> 2;
        bf16* dst = ((seg == 0) ? VTs : VTc)
                    + (((size_t)b * 16 + h) * 64 + hd) * 1024 + s;
        dst[0]    = (bf16)(acc[mi][ni][0] + bi.x);
        dst[1024] = (bf16)(acc[mi][ni][1] + bi.y);
        dst[2048] = (bf16)(acc[mi][ni][2] + bi.z);
        dst[3072] = (bf16)(acc[mi][ni][3] + bi.w);
      }
    }
  }
}

// ---------------- 128² GEMM (BK=32): C[M,N] = A[M,K] @ W[N,K]^T ------------
// 32 KiB LDS -> up to 5 blocks/CU. Double-buffered, PIN'd prefetch.
// grid.z>1: K-split bf16 partials.
__global__ __launch_bounds__(256) void gemm_nt(
    const bf16* __restrict__ A, const bf16* __restrict__ W,
    const float* __restrict__ b0, const float* __restrict__ b1,
    const float* __restrict__ b2, const float* __restrict__ b3,
    bf16* __restrict__ C, int M, int N, int K, int flags, int kc)
{
  __shared__ bf16 As[2][128 * 32];
  __shared__ bf16 Bs[2][128 * 32];
  const int tid  = threadIdx.x;
  const int wave = tid >> 6, lane = tid & 63;
  const int quad = lane >> 4, l16 = lane & 15;

  const int nbx = gridDim.x, nby = gridDim.y, nbz = gridDim.z;
  const int nbyX = nby >> 3;
  const int lin = blockIdx.x + nbx * (blockIdx.y + nby * blockIdx.z);
  const int c = lin & 7;
  int q = lin >> 3;
  const int by = c * nbyX + (q % nbyX); q /= nbyX;
  const int bx = q % nbx; q /= nbx;
  const int bz = q;

  const int m0 = by * 128, n0 = bx * 128;
  const int wm = (wave >> 1) * 64, wn = (wave & 1) * 64;

  f32x4 acc[4][4] = {};

  const int srow4 = lane >> 2;
  const int sgc = ((lane & 3) ^ ((lane >> 3) & 3)) * 8;
  const int kbeg = bz * kc;
  const bf16* Ap = A + (size_t)(m0 + wave * 32 + srow4) * K + kbeg + sgc;
  const bf16* Wp = W + (size_t)(n0 + wave * 32 + srow4) * K + kbeg + sgc;
  const size_t rstep16 = (size_t)16 * K;
  const int woff = (wave * 32) * 32;
  const int g = (quad ^ ((l16 >> 1) & 3)) * 8;

  auto stage = [&](bf16* AsD, bf16* BsD, int k0) {
    GLD(Ap + k0,           AsD + woff);
    GLD(Ap + rstep16 + k0, AsD + woff + 512);
    GLD(Wp + k0,           BsD + woff);
    GLD(Wp + rstep16 + k0, BsD + woff + 512);
  };
  auto compute = [&](const bf16* AsB, const bf16* BsB) {
    bf16x8 wf[4], tf[4];
#pragma unroll
    for (int i = 0; i < 4; ++i)
      wf[i] = *(const bf16x8*)(BsB + (wn + i * 16 + l16) * 32 + g);
#pragma unroll
    for (int i = 0; i < 4; ++i)
      tf[i] = *(const bf16x8*)(AsB + (wm + i * 16 + l16) * 32 + g);
#pragma unroll
    for (int mi = 0; mi < 4; ++mi)
#pragma unroll
      for (int ni = 0; ni < 4; ++ni)
        acc[mi][ni] = __builtin_amdgcn_mfma_f32_16x16x32_bf16(wf[mi], tf[ni], acc[mi][ni], 0, 0, 0);
  };

  stage(As[0], Bs[0], 0);
  pipe_sync();
  int k0 = 0;
  for (; k0 < kc - 64; k0 += 64) {
    stage(As[1], Bs[1], k0 + 32);
    PIN();
    compute(As[0], Bs[0]);
    pipe_sync();
    stage(As[0], Bs[0], k0 + 64);
    PIN();
    compute(As[1], Bs[1]);
    pipe_sync();
  }
  stage(As[1], Bs[1], kc - 32);
  PIN();
  compute(As[0], Bs[0]);
  pipe_sync();
  compute(As[1], Bs[1]);

  if (nbz > 1) {
    bf16* Cp = C + (size_t)bz * M * N;
#pragma unroll
    for (int ni = 0; ni < 4; ++ni) {
      const size_t rowb = (size_t)(m0 + wm + ni * 16 + l16) * N;
#pragma unroll
      for (int mi = 0; mi < 4; ++mi) {
        const int gf = n0 + wn + mi * 16 + quad * 4;
        bf16x4 o; o[0] = (bf16)acc[mi][ni][0]; o[1] = (bf16)acc[mi][ni][1];
        o[2] = (bf16)acc[mi][ni][2]; o[3] = (bf16)acc[mi][ni][3];
        *(bf16x4*)(Cp + rowb + gf) = o;
      }
    }
    return;
  }

  const float* bp[4] = {b0, b1, b2, b3};
  const bool orelu = flags & 1;
#pragma unroll
  for (int ni = 0; ni < 4; ++ni) {
    const size_t rowb = (size_t)(m0 + wm + ni * 16 + l16) * N;
#pragma unroll
    for (int mi = 0; mi < 4; ++mi) {
      const int gf = n0 + wn + mi * 16 + quad * 4;
      const float4 bi = *(const float4*)(bp[gf >> 10] + (gf & 1023));
      float v0 = acc[mi][ni][0] + bi.x, v1 = acc[mi][ni][1] + bi.y;
      float v2 = acc[mi][ni][2] + bi.z, v3 = acc[mi][ni][3] + bi.w;
      if (orelu) {
        v0 = fmaxf(v0, 0.f); v1 = fmaxf(v1, 0.f);
        v2 = fmaxf(v2, 0.f); v3 = fmaxf(v3, 0.f);
      }
      bf16x4 o; o[0] = (bf16)v0; o[1] = (bf16)v1; o[2] = (bf16)v2; o[3] = (bf16)v3;
      *(bf16x4*)(C + rowb + gf) = o;
    }
  }
}

// ---------------- fused attention (register-resident P) ----------------
__global__ __launch_bounds__(256) void attn_kernel(
    const bf16* __restrict__ Q, const bf16* __restrict__ K,
    const bf16* __restrict__ VT, bf16* __restrict__ O)
{
  __shared__ bf16 Kt[2][64 * 64];
  __shared__ bf16 Vt[2][64 * 64];

  const int tid = threadIdx.x, w = tid >> 6, lane = tid & 63;
  const int quad = lane >> 4, l16 = lane & 15;
  const int bh = blockIdx.y, b = bh >> 4;
  const int co = (bh & 15) * HDIM;
  const int sq0 = blockIdx.x * 128 + w * 32;

  bf16x8 qf[2][2];
#pragma unroll
  for (int u = 0; u < 2; ++u) {
    const bf16* qp = Q + ((size_t)(sq0 + u * 16 + l16) * BATCH + b) * 1024 + co + quad * 8;
    qf[u][0] = *(const bf16x8*)qp;
    qf[u][1] = *(const bf16x8*)(qp + 32);
  }

  f32x4 oacc[2][4] = {};
  float lsum[2] = {0.f, 0.f};

  const int srow = lane >> 3;
  const int glog = (lane & 7) ^ srow;
  const int sw = l16 & 7;

  auto stage = [&](bf16* KtD, bf16* VtD, int t0) {
#pragma unroll
    for (int j = 0; j < 2; ++j) {
      const int slot = j * 32 + w * 8 + srow;
      const int m = slot & 15, half = (slot >> 4) & 1, chunk = slot >> 5;
      const int t = chunk * 32 + 8 * (m >> 2) + 4 * half + (m & 3);
      GLD(K + ((size_t)(t0 + t) * BATCH + b) * 1024 + co + glog * 8,
          KtD + (j * 32 + w * 8) * 64);
      const int hd = j * 32 + w * 8 + srow;
      GLD(VT + ((size_t)bh * HDIM + hd) * SEQ + t0 + glog * 8,
          VtD + (j * 32 + w * 8) * 64);
    }
  };

  auto compute = [&](const bf16* KtB, const bf16* VtB) {
#pragma unroll
    for (int c = 0; c < 2; ++c) {
      const bf16* k0 = KtB + (c * 32 + l16) * 64;
      const bf16* k1 = KtB + (c * 32 + 16 + l16) * 64;
      const int g0 = (quad ^ sw) * 8;
      const int g1 = ((4 + quad) ^ sw) * 8;
      bf16x8 ka00 = *(const bf16x8*)(k0 + g0);
      bf16x8 ka01 = *(const bf16x8*)(k0 + g1);
      bf16x8 ka10 = *(const bf16x8*)(k1 + g0);
      bf16x8 ka11 = *(const bf16x8*)(k1 + g1);
      bf16x8 vf[4];
#pragma unroll
      for (int nt = 0; nt < 4; ++nt)
        vf[nt] = *(const bf16x8*)(VtB + (nt * 16 + l16) * 64 + (((c * 4 + quad) ^ sw) * 8));
#pragma unroll
      for (int u = 0; u < 2; ++u) {
        f32x4 c0 = {}, c1 = {};
        c0 = __builtin_amdgcn_mfma_f32_16x16x32_bf16(ka00, qf[u][0], c0, 0, 0, 0);
        c0 = __builtin_amdgcn_mfma_f32_16x16x32_bf16(ka01, qf[u][1], c0, 0, 0, 0);
        c1 = __builtin_amdgcn_mfma_f32_16x16x32_bf16(ka10, qf[u][0], c1, 0, 0, 0);
        c1 = __builtin_amdgcn_mfma_f32_16x16x32_bf16(ka11, qf[u][1], c1, 0, 0, 0);
        bf16x8 pf; float ls = 0.f;
#pragma unroll
        for (int r = 0; r < 4; ++r) {
          float p0 = __expf(c0[r]);
          float p1 = __expf(c1[r]);
          ls += p0 + p1;
          pf[r] = (bf16)p0;
          pf[4 + r] = (bf16)p1;
        }
        lsum[u] += ls;
#pragma unroll
        for (int nt = 0; nt < 4; ++nt)
          oacc[u][nt] = __builtin_amdgcn_mfma_f32_16x16x32_bf16(pf, vf[nt], oacc[u][nt], 0, 0, 0);
      }
    }
  };

  stage(Kt[0], Vt[0], 0);
  pipe_sync();
  int t0 = 0;
  for (; t0 < SEQ - 128; t0 += 128) {
    stage(Kt[1], Vt[1], t0 + 64);
    PIN();
    compute(Kt[0], Vt[0]);
    pipe_sync();
    stage(Kt[0], Vt[0], t0 + 128);
    PIN();
    compute(Kt[1], Vt[1]);
    pipe_sync();
  }
  stage(Kt[1], Vt[1], SEQ - 64);
  PIN();
  compute(Kt[0], Vt[0]);
  pipe_sync();
  compute(Kt[1], Vt[1]);

#pragma unroll
  for (int u = 0; u < 2; ++u) {
    float s = lsum[u];
    s += __shfl_xor(s, 16, 64);
    s += __shfl_xor(s, 32, 64);
#pragma unroll
    for (int r = 0; r < 4; ++r) {
      const float inv = 1.0f / __shfl(s, quad * 4 + r, 64);
      const size_t ro = ((size_t)(sq0 + u * 16 + quad * 4 + r) * BATCH + b) * DMOD + co;
#pragma unroll
      for (int nt = 0; nt < 4; ++nt)
        O[ro + nt * 16 + l16] = (bf16)(oacc[u][nt][r] * inv);
    }
  }
}

// ------- fused (residual + bf16 split-K partials + bias) + layernorm --------
__global__ __launch_bounds__(256) void add_ln_red(
    const float* __restrict__ Xa,
    const bf16* __restrict__ p0, const bf16* __restrict__ p1,
    const bf16* __restrict__ p2, const bf16* __restrict__ p3, int np,
    const float* __restrict__ bias,
    const float* __restrict__ g, const float* __restrict__ beta,
    float* __restrict__ outf, bf16* __restrict__ outb)
{
  const int row = blockIdx.x, tid = threadIdx.x;
  const size_t base = (size_t)row * DMOD;
  float4 a = ((const float4*)(Xa + base))[tid];
  bf16x4 q0 = ((const bf16x4*)(p0 + base))[tid];
  bf16x4 q1 = ((const bf16x4*)(p1 + base))[tid];
  float x0 = a.x + (float)q0[0] + (float)q1[0];
  float x1 = a.y + (float)q0[1] + (float)q1[1];
  float x2 = a.z + (float)q0[2] + (float)q1[2];
  float x3 = a.w + (float)q0[3] + (float)q1[3];
  if (np > 2) {
    bf16x4 q2 = ((const bf16x4*)(p2 + base))[tid];
    bf16x4 q3 = ((const bf16x4*)(p3 + base))[tid];
    x0 += (float)q2[0] + (float)q3[0]; x1 += (float)q2[1] + (float)q3[1];
    x2 += (float)q2[2] + (float)q3[2]; x3 += (float)q2[3] + (float)q3[3];
  }
  float4 bi = ((const float4*)bias)[tid];
  x0 += bi.x; x1 += bi.y; x2 += bi.z; x3 += bi.w;

  float s  = x0 + x1 + x2 + x3;
  float s2 = x0 * x0 + x1 * x1 + x2 * x2 + x3 * x3;
#pragma unroll
  for (int m = 1; m < 64; m <<= 1) { s += __shfl_xor(s, m, 64); s2 += __shfl_xor(s2, m, 64); }
  __shared__ float red[8];
  if ((tid & 63) == 0) { red[tid >> 6] = s; red[4 + (tid >> 6)] = s2; }
  __syncthreads();
  s  = red[0] + red[1] + red[2] + red[3];
  s2 = red[4] + red[5] + red[6] + red[7];
  const float mean = s * (1.0f / DMOD);
  const float var  = s2 * (1.0f / DMOD) - mean * mean;
  const float rs   = rsqrtf(var + 1e-5f);
  float4 gv = ((const float4*)g)[tid];
  float4 bv = ((const float4*)beta)[tid];
  float y0 = (x0 - mean) * rs * gv.x + bv.x;
  float y1 = (x1 - mean) * rs * gv.y + bv.y;
  float y2 = (x2 - mean) * rs * gv.z + bv.z;
  float y3 = (x3 - mean) * rs * gv.w + bv.w;
  float4 o; o.x = y0; o.y = y1; o.z = y2; o.w = y3;
  ((float4*)(outf + base))[tid] = o;
  if (outb) {
    bf16x4 ob; ob[0] = (bf16)y0; ob[1] = (bf16)y1; ob[2] = (bf16)y2; ob[3] = (bf16)y3;
    ((bf16x4*)(outb + base))[tid] = ob;
  }
}

// ---------------- split-K reduce + bias -> bf16 (cross-attn K) --------------
__global__ __launch_bounds__(256) void reduce_cast(
    const bf16* __restrict__ p0, const bf16* __restrict__ p1,
    const float* __restrict__ bias, bf16* __restrict__ out)
{
  const int row = blockIdx.x, tid = threadIdx.x;
  const size_t base = (size_t)row * DMOD;
  bf16x4 a = ((const bf16x4*)(p0 + base))[tid];
  bf16x4 b = ((const bf16x4*)(p1 + base))[tid];
  float4 bi = ((const float4*)bias)[tid];
  bf16x4 o;
  o[0] = (bf16)((float)a[0] + (float)b[0] + bi.x);
  o[1] = (bf16)((float)a[1] + (float)b[1] + bi.y);
  o[2] = (bf16)((float)a[2] + (float)b[2] + bi.z);
  o[3] = (bf16)((float)a[3] + (float)b[3] + bi.w);
  ((bf16x4*)(out + base))[tid] = o;
}

// ---------------- driver ----------------
extern "C" void kernel_launch(void* const* d_in, const int* in_sizes, int n_in,
                              void* d_out, int out_size, void* d_ws, size_t ws_size,
                              hipStream_t stream)
{
  const float* x0    = (const float*)d_in[0];
  const float* enc   = (const float*)d_in[1];
  const float* sa_wq = (const float*)d_in[2];
  const float* sa_bq = (const float*)d_in[3];
  const float* sa_wk = (const float*)d_in[4];
  const float* sa_bk = (const float*)d_in[5];
  const float* sa_wv = (const float*)d_in[6];
  const float* sa_bv = (const float*)d_in[7];
  const float* sa_wo = (const float*)d_in[8];
  const float* sa_bo = (const float*)d_in[9];
  const float* ca_wq = (const float*)d_in[10];
  const float* ca_bq = (const float*)d_in[11];
  const float* ca_wk = (const float*)d_in[12];
  const float* ca_bk = (const float*)d_in[13];
  const float* ca_wv = (const float*)d_in[14];
  const float* ca_bv = (const float*)d_in[15];
  const float* ca_wo = (const float*)d_in[16];
  const float* ca_bo = (const float*)d_in[17];
  const float* w1    = (const float*)d_in[18];
  const float* b1    = (const float*)d_in[19];
  const float* w2    = (const float*)d_in[20];
  const float* b2    = (const float*)d_in[21];
  const float* ln1g  = (const float*)d_in[22];
  const float* ln1b  = (const float*)d_in[23];
  const float* ln2g  = (const float*)d_in[24];
  const float* ln2b  = (const float*)d_in[25];
  const float* ln3g  = (const float*)d_in[26];
  const float* ln3b  = (const float*)d_in[27];

  char* ws = (char*)d_ws;
  size_t off = 0;
  auto take = [&](size_t bytes) -> char* {
    char* p = ws + off; off += (bytes + 255) & ~(size_t)255; return p;
  };
  const size_t WEL = (size_t)DMOD * DMOD;
  const size_t ACT = (size_t)NTOK * DMOD;   // 4M elems
  // weights (persistent), 32 MB
  bf16* Wqkv_s = (bf16*)take(3 * WEL * 2);
  bf16* Wo_s   = (bf16*)take(WEL * 2);
  bf16* Wqv_c  = (bf16*)take(2 * WEL * 2);
  bf16* Wk_c   = (bf16*)take(WEL * 2);
  bf16* Wo_c   = (bf16*)take(WEL * 2);
  bf16* W1b    = (bf16*)take(4 * WEL * 2);
  bf16* W2b    = (bf16*)take(4 * WEL * 2);
  // activations (8 MB each unless noted)
  bf16* x0b  = (bf16*)take(ACT * 2);   // -> O-proj partial0
  bf16* encb = (bf16*)take(ACT * 2);   // -> O-proj partial1
  bf16* Qs   = (bf16*)take(ACT * 2);   // -> crossK p0 / FFN2 p0
  bf16* Ks   = (bf16*)take(ACT * 2);   // -> crossK p1 / FFN2 p1
  bf16* VTs  = (bf16*)take(ACT * 2);   // -> FFN2 p2
  bf16* Qc   = (bf16*)take(ACT * 2);   // -> FFN2 p3
  bf16* VTc  = (bf16*)take(ACT * 2);
  bf16* Kc   = (bf16*)take(ACT * 2);
  bf16* ctx  = (bf16*)take(ACT * 2);
  float* out1f = (float*)take(ACT * 4);   // 16 MB; also out2 residual (in-place)
  bf16*  out1b = (bf16*)take(ACT * 2);    // also out2b (in-place)
  bf16*  Hff   = (bf16*)take((size_t)NTOK * DFF * 2);  // 32 MB
  // partial aliases
  bf16* pA = x0b;  bf16* pB = encb;            // O-proj splits
  bf16* pC = Qs;   bf16* pD = Ks;              // cross-K split
  bf16* f0 = Qs;   bf16* f1 = Ks;  bf16* f2 = VTs;  bf16* f3 = Qc;  // FFN2
  (void)ws_size; (void)in_sizes; (void)n_in; (void)out_size;  // ~160 MB

  // cast: 24 uniform chunks of nw float4s (grid 1024x24, zero dead blocks)
  CastArgs cargs;
  const int nw = (int)(WEL / 4);   // 262144 float4s per chunk
  int si = 0;
  auto addseg = [&](const float* s, bf16* d, int chunks) {
    for (int c = 0; c < chunks; ++c) {
      cargs.seg[si].src = s + (size_t)c * nw * 4;
      cargs.seg[si].dst = d + (size_t)c * nw * 4;
      cargs.seg[si].n4  = nw;
      ++si;
    }
  };
  addseg(x0,    x0b,            4);
  addseg(enc,   encb,           4);
  addseg(sa_wq, Wqkv_s,         1);
  addseg(sa_wk, Wqkv_s + WEL,   1);
  addseg(sa_wv, Wqkv_s + 2*WEL, 1);
  addseg(sa_wo, Wo_s,           1);
  addseg(ca_wq, Wqv_c,          1);
  addseg(ca_wv, Wqv_c + WEL,    1);
  addseg(ca_wk, Wk_c,           1);
  addseg(ca_wo, Wo_c,           1);
  addseg(w1,    W1b,            4);
  addseg(w2,    W2b,            4);
  cast_multi<<<dim3(nw / 256, 24), 256, 0, stream>>>(cargs);

  auto gemm = [&](const bf16* A, const bf16* Wt,
                  const float* bb0, const float* bb1, const float* bb2, const float* bb3,
                  bf16* Cp, int M, int N, int Kd, int flags, int nz) {
    gemm_nt<<<dim3(N / 128, M / 128, nz), 256, 0, stream>>>(
        A, Wt, bb0, bb1, bb2, bb3, Cp, M, N, Kd, flags, Kd / nz);
  };

  // 1. merged self-QKV + cross-QV (BK=32 kernel, 1280 blocks = 5/CU exact)
  gemm_qkv<<<dim3(1280), 256, 0, stream>>>(
      x0b, encb, Wqkv_s, Wqv_c, sa_bq, sa_bk, sa_bv, ca_bq, ca_bv,
      Qs, Ks, VTs, Qc, VTc);
  // 2. self attention
  attn_kernel<<<dim3(SEQ / 128, BATCH * NHEAD), 256, 0, stream>>>(Qs, Ks, VTs, ctx);
  // 3. self O-proj split-2 (bf16 partials into dead x0b/encb)
  gemm(ctx, Wo_s, nullptr, nullptr, nullptr, nullptr, pA, NTOK, DMOD, DMOD, 0, 2);
  // 4. LN1(x0 + p + sa_bo)
  add_ln_red<<<dim3(NTOK), 256, 0, stream>>>(x0, pA, pB, nullptr, nullptr, 2,
                                             sa_bo, ln1g, ln1b, out1f, out1b);
  // 5. cross K from out1, split-2 (partials into dead Qs/Ks)
  gemm(out1b, Wk_c, nullptr, nullptr, nullptr, nullptr, pC, NTOK, DMOD, DMOD, 0, 2);
  reduce_cast<<<dim3(NTOK), 256, 0, stream>>>(pC, pD, ca_bk, Kc);
  // 6. cross attention
  attn_kernel<<<dim3(SEQ / 128, BATCH * NHEAD), 256, 0, stream>>>(Qc, Kc, VTc, ctx);
  // 7. cross O-proj split-2
  gemm(ctx, Wo_c, nullptr, nullptr, nullptr, nullptr, pA, NTOK, DMOD, DMOD, 0, 2);
  // 8. LN2 (in-place residual/bf16 reuse)
  add_ln_red<<<dim3(NTOK), 256, 0, stream>>>(out1f, pA, pB, nullptr, nullptr, 2,
                                             ca_bo, ln2g, ln2b, out1f, out1b);
  // 9. FFN1 + ReLU (BK=32 kernel, 1024 blocks -> fully resident)
  gemm(out1b, W1b, b1, b1 + 1024, b1 + 2048, b1 + 3072, Hff, NTOK, DFF, DMOD, 1, 1);
  // 10. FFN2 split-4 (BK=32 kernel; partials into dead Qs/Ks/VTs/Qc)
  gemm(Hff, W2b, nullptr, nullptr, nullptr, nullptr, f0, NTOK, DMOD, DFF, 0, 4);
  // 11. LN3 -> d_out (f32)
  add_ln_red<<<dim3(NTOK), 256, 0, stream>>>(out1f, f0, f1, f2, f3, 4,
                                             b2, ln3g, ln3b, (float*)d_out, nullptr);
}

// Round 8
// 466.635 us; speedup vs baseline: 1.0586x; 1.0586x over previous
//
#include <hip/hip_runtime.h>
#include <hip/hip_bf16.h>
#include <cstdint>
#include <cstddef>

// DecoderLayer: S=1024 B=4 D=1024 H=16 HD=64 DFF=4096, all f32 in/out.
// R14: measured-best hybrid. gemm_qkv keeps R13's BK=32 (69.5us, 32KiB LDS,
// 1280 blocks = 5x256 zero-tail; best measured qkv). gemm_nt reverts to
// R12's BK=64 (BK=32 regressed its 4 call sites ~9us net: doubled barrier
// rate at unchanged ~3-blocks/CU residency -- unified VGPR+AGPR file caps
// occupancy at ~136 regs/wave, not LDS). attn/LN/cast unchanged.
// Session state: R8..R13 all in 476-494us band; GEMMs at the documented
// 2-phase ~650TF sync plateau; deep-pipeline ports nulled 3x at K=1024.

typedef __bf16 bf16;
typedef __attribute__((ext_vector_type(8))) __bf16 bf16x8;
typedef __attribute__((ext_vector_type(4))) __bf16 bf16x4;
typedef __attribute__((ext_vector_type(4))) float f32x4;

#define SEQ   1024
#define BATCH 4
#define DMOD  1024
#define NHEAD 16
#define HDIM  64
#define NTOK  (SEQ*BATCH)
#define DFF   4096

#define GLD(gp, lp) __builtin_amdgcn_global_load_lds( \
    (__attribute__((address_space(1))) void*)(gp),    \
    (__attribute__((address_space(3))) void*)(lp), 16, 0, 0)

#define PIN() __builtin_amdgcn_sched_barrier(0)

static __device__ __forceinline__ void pipe_sync() {
  asm volatile("s_waitcnt vmcnt(0)" ::: "memory");
  __builtin_amdgcn_s_barrier();
  asm volatile("" ::: "memory");
}

// ---------------- batched f32 -> bf16 cast (24 uniform chunks) --------------
struct CastSeg { const float* src; bf16* dst; int n4; };
struct CastArgs { CastSeg seg[24]; };

__global__ __launch_bounds__(256) void cast_multi(CastArgs a) {
  CastSeg s = a.seg[blockIdx.y];
  int i = blockIdx.x * 256 + threadIdx.x;
  if (i < s.n4) {
    float4 v = ((const float4*)s.src)[i];
    bf16x4 o; o[0] = (bf16)v.x; o[1] = (bf16)v.y; o[2] = (bf16)v.z; o[3] = (bf16)v.w;
    ((bf16x4*)s.dst)[i] = o;
  }
}

// ---------------- merged QKV(self) + QV(cross) GEMM (BK=32, R13) -----------
// 1280 blocks (5/CU x 256 CUs, zero tail): id<768 -> self (A=x0b,
// W=[wq;wk;wv], N=3072); else cross (A=encb, W=[wq;wv], N=2048).
// Q scaled by 0.125 (incl bias). V written transposed: VT[bh][hd][s].
__global__ __launch_bounds__(256) void gemm_qkv(
    const bf16* __restrict__ x0b, const bf16* __restrict__ encb,
    const bf16* __restrict__ Wqkv, const bf16* __restrict__ Wqv,
    const float* __restrict__ sbq, const float* __restrict__ sbk,
    const float* __restrict__ sbv,
    const float* __restrict__ cbq, const float* __restrict__ cbv,
    bf16* __restrict__ Qs, bf16* __restrict__ Ks, bf16* __restrict__ VTs,
    bf16* __restrict__ Qc, bf16* __restrict__ VTc)
{
  __shared__ bf16 As[2][128 * 32];
  __shared__ bf16 Bs[2][128 * 32];
  const int tid  = threadIdx.x;
  const int wave = tid >> 6, lane = tid & 63;
  const int quad = lane >> 4, l16 = lane & 15;

  int id = blockIdx.x, seg, bx, by;
  const bf16 *A, *W;
  if (id < 768) {
    seg = 0; const int c = id & 7, q = id >> 3;
    by = c * 4 + (q & 3); bx = q >> 2;  // by fastest (L2 window), bx 0..23
    A = x0b; W = Wqkv;
  } else {
    id -= 768;
    seg = 1; const int c = id & 7, q = id >> 3;
    by = c * 4 + (q & 3); bx = q >> 2;  // bx 0..15
    A = encb; W = Wqv;
  }
  const int K = 1024;
  const int m0 = by * 128, n0 = bx * 128;
  const int wm = (wave >> 1) * 64, wn = (wave & 1) * 64;

  f32x4 acc[4][4] = {};
  const int srow4 = lane >> 2;                       // 0..15
  const int sgc = ((lane & 3) ^ ((lane >> 3) & 3)) * 8;  // swizzled src chunk
  const bf16* Ap = A + (size_t)(m0 + wave * 32 + srow4) * K + sgc;
  const bf16* Wp = W + (size_t)(n0 + wave * 32 + srow4) * K + sgc;
  const size_t rstep16 = (size_t)16 * K;
  const int woff = (wave * 32) * 32;
  const int g = (quad ^ ((l16 >> 1) & 3)) * 8;       // fragment-read slot

  auto stage = [&](bf16* AsD, bf16* BsD, int k0) {
    GLD(Ap + k0,           AsD + woff);
    GLD(Ap + rstep16 + k0, AsD + woff + 512);
    GLD(Wp + k0,           BsD + woff);
    GLD(Wp + rstep16 + k0, BsD + woff + 512);
  };
  auto compute = [&](const bf16* AsB, const bf16* BsB) {
    bf16x8 wf[4], tf[4];
#pragma unroll
    for (int i = 0; i < 4; ++i)
      wf[i] = *(const bf16x8*)(BsB + (wn + i * 16 + l16) * 32 + g);
#pragma unroll
    for (int i = 0; i < 4; ++i)
      tf[i] = *(const bf16x8*)(AsB + (wm + i * 16 + l16) * 32 + g);
#pragma unroll
    for (int mi = 0; mi < 4; ++mi)
#pragma unroll
      for (int ni = 0; ni < 4; ++ni)
        acc[mi][ni] = __builtin_amdgcn_mfma_f32_16x16x32_bf16(wf[mi], tf[ni], acc[mi][ni], 0, 0, 0);
  };

  stage(As[0], Bs[0], 0);
  pipe_sync();
  int k0 = 0;
  for (; k0 < K - 64; k0 += 64) {
    stage(As[1], Bs[1], k0 + 32);
    PIN();
    compute(As[0], Bs[0]);
    pipe_sync();
    stage(As[0], Bs[0], k0 + 64);
    PIN();
    compute(As[1], Bs[1]);
    pipe_sync();
  }
  stage(As[1], Bs[1], K - 32);
  PIN();
  compute(As[0], Bs[0]);
  pipe_sync();
  compute(As[1], Bs[1]);

  const int region = n0 >> 10;   // block-uniform: 0=Q, 1=K(self), last=V
  const bool isV = (seg == 0) ? (region == 2) : (region == 1);
#pragma unroll
  for (int ni = 0; ni < 4; ++ni) {
    const int i = m0 + wm + ni * 16 + l16;       // token (s*4+b)
#pragma unroll
    for (int mi = 0; mi < 4; ++mi) {
      const int gf = n0 + wn + mi * 16 + quad * 4;
      const int lf = gf & 1023;
      if (!isV) {
        if (region == 0) {   // Q (scaled)
          const float* bq = (seg == 0) ? sbq : cbq;
          const float4 bi = *(const float4*)(bq + lf);
          bf16* dst = ((seg == 0) ? Qs : Qc) + (size_t)i * 1024 + lf;
          bf16x4 o;
          o[0] = (bf16)((acc[mi][ni][0] + bi.x) * 0.125f);
          o[1] = (bf16)((acc[mi][ni][1] + bi.y) * 0.125f);
          o[2] = (bf16)((acc[mi][ni][2] + bi.z) * 0.125f);
          o[3] = (bf16)((acc[mi][ni][3] + bi.w) * 0.125f);
          *(bf16x4*)dst = o;
        } else {             // K (self only)
          const float4 bi = *(const float4*)(sbk + lf);
          bf16x4 o;
          o[0] = (bf16)(acc[mi][ni][0] + bi.x);
          o[1] = (bf16)(acc[mi][ni][1] + bi.y);
          o[2] = (bf16)(acc[mi][ni][2] + bi.z);
          o[3] = (bf16)(acc[mi][ni][3] + bi.w);
          *(bf16x4*)(Ks + (size_t)i * 1024 + lf) = o;
        }
      } else {               // V -> transposed VT[bh][hd][s]
        const float* bv = (seg == 0) ? sbv : cbv;
        const float4 bi = *(const float4*)(bv + lf);
        const int h = lf >> 6, hd = lf & 63;
        const int b = i & 3, s = i >> 2;
        bf16* dst = ((seg == 0) ? VTs : VTc)
                    + (((size_t)b * 16 + h) * 64 + hd) * 1024 + s;
        dst[0]    = (bf16)(acc[mi][ni][0] + bi.x);
        dst[1024] = (bf16)(acc[mi][ni][1] + bi.y);
        dst[2048] = (bf16)(acc[mi][ni][2] + bi.z);
        dst[3072] = (bf16)(acc[mi][ni][3] + bi.w);
      }
    }
  }
}

// ---------------- 128² GEMM (BK=64, R12): C[M,N] = A[M,K] @ W[N,K]^T -------
// BK=64, 4 waves x 64x64, XOR-swizzled LDS, double-buffered staging with
// pinned issue-before-compute. grid.z>1: K-split bf16 partials.
__global__ __launch_bounds__(256) void gemm_nt(
    const bf16* __restrict__ A, const bf16* __restrict__ W,
    const float* __restrict__ b0, const float* __restrict__ b1,
    const float* __restrict__ b2, const float* __restrict__ b3,
    bf16* __restrict__ C, int M, int N, int K, int flags, int kc)
{
  __shared__ bf16 As[2][128 * 64];
  __shared__ bf16 Bs[2][128 * 64];
  const int tid  = threadIdx.x;
  const int wave = tid >> 6, lane = tid & 63;
  const int quad = lane >> 4, l16 = lane & 15;

  const int nbx = gridDim.x, nby = gridDim.y, nbz = gridDim.z;
  const int nbyX = nby >> 3;
  const int lin = blockIdx.x + nbx * (blockIdx.y + nby * blockIdx.z);
  const int c = lin & 7;
  int q = lin >> 3;
  const int by = c * nbyX + (q % nbyX); q /= nbyX;
  const int bx = q % nbx; q /= nbx;
  const int bz = q;

  const int m0 = by * 128, n0 = bx * 128;
  const int wm = (wave >> 1) * 64, wn = (wave & 1) * 64;

  f32x4 acc[4][4] = {};

  const int srow8 = lane >> 3;
  const int sg = ((lane & 7) ^ srow8) * 8;
  const int kbeg = bz * kc;
  const bf16* Ap = A + (size_t)(m0 + wave * 32 + srow8) * K + kbeg + sg;
  const bf16* Wp = W + (size_t)(n0 + wave * 32 + srow8) * K + kbeg + sg;
  const size_t rstep8 = (size_t)8 * K;
  const int woff = (wave * 32) * 64;
  const int fsw = l16 & 7;

  auto stage = [&](bf16* AsD, bf16* BsD, int k0) {
#pragma unroll
    for (int j = 0; j < 4; ++j) {
      GLD(Ap + j * rstep8 + k0, AsD + woff + j * 8 * 64);
      GLD(Wp + j * rstep8 + k0, BsD + woff + j * 8 * 64);
    }
  };
  auto compute = [&](const bf16* AsB, const bf16* BsB) {
#pragma unroll
    for (int ks = 0; ks < 2; ++ks) {
      const int g = ((ks * 4 + quad) ^ fsw) * 8;
      bf16x8 wf[4], tf[4];
#pragma unroll
      for (int i = 0; i < 4; ++i)
        wf[i] = *(const bf16x8*)(BsB + (wn + i * 16 + l16) * 64 + g);
#pragma unroll
      for (int i = 0; i < 4; ++i)
        tf[i] = *(const bf16x8*)(AsB + (wm + i * 16 + l16) * 64 + g);
#pragma unroll
      for (int mi = 0; mi < 4; ++mi)
#pragma unroll
        for (int ni = 0; ni < 4; ++ni)
          acc[mi][ni] = __builtin_amdgcn_mfma_f32_16x16x32_bf16(wf[mi], tf[ni], acc[mi][ni], 0, 0, 0);
    }
  };

  stage(As[0], Bs[0], 0);
  pipe_sync();
  int k0 = 0;
  for (; k0 < kc - 128; k0 += 128) {
    stage(As[1], Bs[1], k0 + 64);
    PIN();
    compute(As[0], Bs[0]);
    pipe_sync();
    stage(As[0], Bs[0], k0 + 128);
    PIN();
    compute(As[1], Bs[1]);
    pipe_sync();
  }
  stage(As[1], Bs[1], k0 + 64);
  PIN();
  compute(As[0], Bs[0]);
  pipe_sync();
  compute(As[1], Bs[1]);

  if (nbz > 1) {
    bf16* Cp = C + (size_t)bz * M * N;
#pragma unroll
    for (int ni = 0; ni < 4; ++ni) {
      const size_t rowb = (size_t)(m0 + wm + ni * 16 + l16) * N;
#pragma unroll
      for (int mi = 0; mi < 4; ++mi) {
        const int gf = n0 + wn + mi * 16 + quad * 4;
        bf16x4 o; o[0] = (bf16)acc[mi][ni][0]; o[1] = (bf16)acc[mi][ni][1];
        o[2] = (bf16)acc[mi][ni][2]; o[3] = (bf16)acc[mi][ni][3];
        *(bf16x4*)(Cp + rowb + gf) = o;
      }
    }
    return;
  }

  const float* bp[4] = {b0, b1, b2, b3};
  const bool orelu = flags & 1;
#pragma unroll
  for (int ni = 0; ni < 4; ++ni) {
    const size_t rowb = (size_t)(m0 + wm + ni * 16 + l16) * N;
#pragma unroll
    for (int mi = 0; mi < 4; ++mi) {
      const int gf = n0 + wn + mi * 16 + quad * 4;
      const float4 bi = *(const float4*)(bp[gf >> 10] + (gf & 1023));
      float v0 = acc[mi][ni][0] + bi.x, v1 = acc[mi][ni][1] + bi.y;
      float v2 = acc[mi][ni][2] + bi.z, v3 = acc[mi][ni][3] + bi.w;
      if (orelu) {
        v0 = fmaxf(v0, 0.f); v1 = fmaxf(v1, 0.f);
        v2 = fmaxf(v2, 0.f); v3 = fmaxf(v3, 0.f);
      }
      bf16x4 o; o[0] = (bf16)v0; o[1] = (bf16)v1; o[2] = (bf16)v2; o[3] = (bf16)v3;
      *(bf16x4*)(C + rowb + gf) = o;
    }
  }
}

// ---------------- fused attention (register-resident P) ----------------
__global__ __launch_bounds__(256) void attn_kernel(
    const bf16* __restrict__ Q, const bf16* __restrict__ K,
    const bf16* __restrict__ VT, bf16* __restrict__ O)
{
  __shared__ bf16 Kt[2][64 * 64];
  __shared__ bf16 Vt[2][64 * 64];

  const int tid = threadIdx.x, w = tid >> 6, lane = tid & 63;
  const int quad = lane >> 4, l16 = lane & 15;
  const int bh = blockIdx.y, b = bh >> 4;
  const int co = (bh & 15) * HDIM;
  const int sq0 = blockIdx.x * 128 + w * 32;

  bf16x8 qf[2][2];
#pragma unroll
  for (int u = 0; u < 2; ++u) {
    const bf16* qp = Q + ((size_t)(sq0 + u * 16 + l16) * BATCH + b) * 1024 + co + quad * 8;
    qf[u][0] = *(const bf16x8*)qp;
    qf[u][1] = *(const bf16x8*)(qp + 32);
  }

  f32x4 oacc[2][4] = {};
  float lsum[2] = {0.f, 0.f};

  const int srow = lane >> 3;
  const int glog = (lane & 7) ^ srow;
  const int sw = l16 & 7;

  auto stage = [&](bf16* KtD, bf16* VtD, int t0) {
#pragma unroll
    for (int j = 0; j < 2; ++j) {
      const int slot = j * 32 + w * 8 + srow;
      const int m = slot & 15, half = (slot >> 4) & 1, chunk = slot >> 5;
      const int t = chunk * 32 + 8 * (m >> 2) + 4 * half + (m & 3);
      GLD(K + ((size_t)(t0 + t) * BATCH + b) * 1024 + co + glog * 8,
          KtD + (j * 32 + w * 8) * 64);
      const int hd = j * 32 + w * 8 + srow;
      GLD(VT + ((size_t)bh * HDIM + hd) * SEQ + t0 + glog * 8,
          VtD + (j * 32 + w * 8) * 64);
    }
  };

  auto compute = [&](const bf16* KtB, const bf16* VtB) {
#pragma unroll
    for (int c = 0; c < 2; ++c) {
      const bf16* k0 = KtB + (c * 32 + l16) * 64;
      const bf16* k1 = KtB + (c * 32 + 16 + l16) * 64;
      const int g0 = (quad ^ sw) * 8;
      const int g1 = ((4 + quad) ^ sw) * 8;
      bf16x8 ka00 = *(const bf16x8*)(k0 + g0);
      bf16x8 ka01 = *(const bf16x8*)(k0 + g1);
      bf16x8 ka10 = *(const bf16x8*)(k1 + g0);
      bf16x8 ka11 = *(const bf16x8*)(k1 + g1);
      bf16x8 vf[4];
#pragma unroll
      for (int nt = 0; nt < 4; ++nt)
        vf[nt] = *(const bf16x8*)(VtB + (nt * 16 + l16) * 64 + (((c * 4 + quad) ^ sw) * 8));
#pragma unroll
      for (int u = 0; u < 2; ++u) {
        f32x4 c0 = {}, c1 = {};
        c0 = __builtin_amdgcn_mfma_f32_16x16x32_bf16(ka00, qf[u][0], c0, 0, 0, 0);
        c0 = __builtin_amdgcn_mfma_f32_16x16x32_bf16(ka01, qf[u][1], c0, 0, 0, 0);
        c1 = __builtin_amdgcn_mfma_f32_16x16x32_bf16(ka10, qf[u][0], c1, 0, 0, 0);
        c1 = __builtin_amdgcn_mfma_f32_16x16x32_bf16(ka11, qf[u][1], c1, 0, 0, 0);
        bf16x8 pf; float ls = 0.f;
#pragma unroll
        for (int r = 0; r < 4; ++r) {
          float p0 = __expf(c0[r]);
          float p1 = __expf(c1[r]);
          ls += p0 + p1;
          pf[r] = (bf16)p0;
          pf[4 + r] = (bf16)p1;
        }
        lsum[u] += ls;
#pragma unroll
        for (int nt = 0; nt < 4; ++nt)
          oacc[u][nt] = __builtin_amdgcn_mfma_f32_16x16x32_bf16(pf, vf[nt], oacc[u][nt], 0, 0, 0);
      }
    }
  };

  stage(Kt[0], Vt[0], 0);
  pipe_sync();
  int t0 = 0;
  for (; t0 < SEQ - 128; t0 += 128) {
    stage(Kt[1], Vt[1], t0 + 64);
    PIN();
    compute(Kt[0], Vt[0]);
    pipe_sync();
    stage(Kt[0], Vt[0], t0 + 128);
    PIN();
    compute(Kt[1], Vt[1]);
    pipe_sync();
  }
  stage(Kt[1], Vt[1], SEQ - 64);
  PIN();
  compute(Kt[0], Vt[0]);
  pipe_sync();
  compute(Kt[1], Vt[1]);

#pragma unroll
  for (int u = 0; u < 2; ++u) {
    float s = lsum[u];
    s += __shfl_xor(s, 16, 64);
    s += __shfl_xor(s, 32, 64);
#pragma unroll
    for (int r = 0; r < 4; ++r) {
      const float inv = 1.0f / __shfl(s, quad * 4 + r, 64);
      const size_t ro = ((size_t)(sq0 + u * 16 + quad * 4 + r) * BATCH + b) * DMOD + co;
#pragma unroll
      for (int nt = 0; nt < 4; ++nt)
        O[ro + nt * 16 + l16] = (bf16)(oacc[u][nt][r] * inv);
    }
  }
}

// ------- fused (residual + bf16 split-K partials + bias) + layernorm --------
__global__ __launch_bounds__(256) void add_ln_red(
    const float* __restrict__ Xa,
    const bf16* __restrict__ p0, const bf16* __restrict__ p1,
    const bf16* __restrict__ p2, const bf16* __restrict__ p3, int np,
    const float* __restrict__ bias,
    const float* __restrict__ g, const float* __restrict__ beta,
    float* __restrict__ outf, bf16* __restrict__ outb)
{
  const int row = blockIdx.x, tid = threadIdx.x;
  const size_t base = (size_t)row * DMOD;
  float4 a = ((const float4*)(Xa + base))[tid];
  bf16x4 q0 = ((const bf16x4*)(p0 + base))[tid];
  bf16x4 q1 = ((const bf16x4*)(p1 + base))[tid];
  float x0 = a.x + (float)q0[0] + (float)q1[0];
  float x1 = a.y + (float)q0[1] + (float)q1[1];
  float x2 = a.z + (float)q0[2] + (float)q1[2];
  float x3 = a.w + (float)q0[3] + (float)q1[3];
  if (np > 2) {
    bf16x4 q2 = ((const bf16x4*)(p2 + base))[tid];
    bf16x4 q3 = ((const bf16x4*)(p3 + base))[tid];
    x0 += (float)q2[0] + (float)q3[0]; x1 += (float)q2[1] + (float)q3[1];
    x2 += (float)q2[2] + (float)q3[2]; x3 += (float)q2[3] + (float)q3[3];
  }
  float4 bi = ((const float4*)bias)[tid];
  x0 += bi.x; x1 += bi.y; x2 += bi.z; x3 += bi.w;

  float s  = x0 + x1 + x2 + x3;
  float s2 = x0 * x0 + x1 * x1 + x2 * x2 + x3 * x3;
#pragma unroll
  for (int m = 1; m < 64; m <<= 1) { s += __shfl_xor(s, m, 64); s2 += __shfl_xor(s2, m, 64); }
  __shared__ float red[8];
  if ((tid & 63) == 0) { red[tid >> 6] = s; red[4 + (tid >> 6)] = s2; }
  __syncthreads();
  s  = red[0] + red[1] + red[2] + red[3];
  s2 = red[4] + red[5] + red[6] + red[7];
  const float mean = s * (1.0f / DMOD);
  const float var  = s2 * (1.0f / DMOD) - mean * mean;
  const float rs   = rsqrtf(var + 1e-5f);
  float4 gv = ((const float4*)g)[tid];
  float4 bv = ((const float4*)beta)[tid];
  float y0 = (x0 - mean) * rs * gv.x + bv.x;
  float y1 = (x1 - mean) * rs * gv.y + bv.y;
  float y2 = (x2 - mean) * rs * gv.z + bv.z;
  float y3 = (x3 - mean) * rs * gv.w + bv.w;
  float4 o; o.x = y0; o.y = y1; o.z = y2; o.w = y3;
  ((float4*)(outf + base))[tid] = o;
  if (outb) {
    bf16x4 ob; ob[0] = (bf16)y0; ob[1] = (bf16)y1; ob[2] = (bf16)y2; ob[3] = (bf16)y3;
    ((bf16x4*)(outb + base))[tid] = ob;
  }
}

// ---------------- split-K reduce + bias -> bf16 (cross-attn K) --------------
__global__ __launch_bounds__(256) void reduce_cast(
    const bf16* __restrict__ p0, const bf16* __restrict__ p1,
    const float* __restrict__ bias, bf16* __restrict__ out)
{
  const int row = blockIdx.x, tid = threadIdx.x;
  const size_t base = (size_t)row * DMOD;
  bf16x4 a = ((const bf16x4*)(p0 + base))[tid];
  bf16x4 b = ((const bf16x4*)(p1 + base))[tid];
  float4 bi = ((const float4*)bias)[tid];
  bf16x4 o;
  o[0] = (bf16)((float)a[0] + (float)b[0] + bi.x);
  o[1] = (bf16)((float)a[1] + (float)b[1] + bi.y);
  o[2] = (bf16)((float)a[2] + (float)b[2] + bi.z);
  o[3] = (bf16)((float)a[3] + (float)b[3] + bi.w);
  ((bf16x4*)(out + base))[tid] = o;
}

// ---------------- driver ----------------
extern "C" void kernel_launch(void* const* d_in, const int* in_sizes, int n_in,
                              void* d_out, int out_size, void* d_ws, size_t ws_size,
                              hipStream_t stream)
{
  const float* x0    = (const float*)d_in[0];
  const float* enc   = (const float*)d_in[1];
  const float* sa_wq = (const float*)d_in[2];
  const float* sa_bq = (const float*)d_in[3];
  const float* sa_wk = (const float*)d_in[4];
  const float* sa_bk = (const float*)d_in[5];
  const float* sa_wv = (const float*)d_in[6];
  const float* sa_bv = (const float*)d_in[7];
  const float* sa_wo = (const float*)d_in[8];
  const float* sa_bo = (const float*)d_in[9];
  const float* ca_wq = (const float*)d_in[10];
  const float* ca_bq = (const float*)d_in[11];
  const float* ca_wk = (const float*)d_in[12];
  const float* ca_bk = (const float*)d_in[13];
  const float* ca_wv = (const float*)d_in[14];
  const float* ca_bv = (const float*)d_in[15];
  const float* ca_wo = (const float*)d_in[16];
  const float* ca_bo = (const float*)d_in[17];
  const float* w1    = (const float*)d_in[18];
  const float* b1    = (const float*)d_in[19];
  const float* w2    = (const float*)d_in[20];
  const float* b2    = (const float*)d_in[21];
  const float* ln1g  = (const float*)d_in[22];
  const float* ln1b  = (const float*)d_in[23];
  const float* ln2g  = (const float*)d_in[24];
  const float* ln2b  = (const float*)d_in[25];
  const float* ln3g  = (const float*)d_in[26];
  const float* ln3b  = (const float*)d_in[27];

  char* ws = (char*)d_ws;
  size_t off = 0;
  auto take = [&](size_t bytes) -> char* {
    char* p = ws + off; off += (bytes + 255) & ~(size_t)255; return p;
  };
  const size_t WEL = (size_t)DMOD * DMOD;
  const size_t ACT = (size_t)NTOK * DMOD;   // 4M elems
  // weights (persistent), 32 MB
  bf16* Wqkv_s = (bf16*)take(3 * WEL * 2);
  bf16* Wo_s   = (bf16*)take(WEL * 2);
  bf16* Wqv_c  = (bf16*)take(2 * WEL * 2);
  bf16* Wk_c   = (bf16*)take(WEL * 2);
  bf16* Wo_c   = (bf16*)take(WEL * 2);
  bf16* W1b    = (bf16*)take(4 * WEL * 2);
  bf16* W2b    = (bf16*)take(4 * WEL * 2);
  // activations (8 MB each unless noted)
  bf16* x0b  = (bf16*)take(ACT * 2);   // -> O-proj partial0
  bf16* encb = (bf16*)take(ACT * 2);   // -> O-proj partial1
  bf16* Qs   = (bf16*)take(ACT * 2);   // -> crossK p0 / FFN2 p0
  bf16* Ks   = (bf16*)take(ACT * 2);   // -> crossK p1 / FFN2 p1
  bf16* VTs  = (bf16*)take(ACT * 2);   // -> FFN2 p2
  bf16* Qc   = (bf16*)take(ACT * 2);   // -> FFN2 p3
  bf16* VTc  = (bf16*)take(ACT * 2);
  bf16* Kc   = (bf16*)take(ACT * 2);
  bf16* ctx  = (bf16*)take(ACT * 2);
  float* out1f = (float*)take(ACT * 4);   // 16 MB; also out2 residual (in-place)
  bf16*  out1b = (bf16*)take(ACT * 2);    // also out2b (in-place)
  bf16*  Hff   = (bf16*)take((size_t)NTOK * DFF * 2);  // 32 MB
  // partial aliases
  bf16* pA = x0b;  bf16* pB = encb;            // O-proj splits
  bf16* pC = Qs;   bf16* pD = Ks;              // cross-K split
  bf16* f0 = Qs;   bf16* f1 = Ks;  bf16* f2 = VTs;  bf16* f3 = Qc;  // FFN2
  (void)ws_size; (void)in_sizes; (void)n_in; (void)out_size;  // ~160 MB

  // cast: 24 uniform chunks of nw float4s (grid 1024x24, zero dead blocks)
  CastArgs cargs;
  const int nw = (int)(WEL / 4);   // 262144 float4s per chunk
  int si = 0;
  auto addseg = [&](const float* s, bf16* d, int chunks) {
    for (int c = 0; c < chunks; ++c) {
      cargs.seg[si].src = s + (size_t)c * nw * 4;
      cargs.seg[si].dst = d + (size_t)c * nw * 4;
      cargs.seg[si].n4  = nw;
      ++si;
    }
  };
  addseg(x0,    x0b,            4);
  addseg(enc,   encb,           4);
  addseg(sa_wq, Wqkv_s,         1);
  addseg(sa_wk, Wqkv_s + WEL,   1);
  addseg(sa_wv, Wqkv_s + 2*WEL, 1);
  addseg(sa_wo, Wo_s,           1);
  addseg(ca_wq, Wqv_c,          1);
  addseg(ca_wv, Wqv_c + WEL,    1);
  addseg(ca_wk, Wk_c,           1);
  addseg(ca_wo, Wo_c,           1);
  addseg(w1,    W1b,            4);
  addseg(w2,    W2b,            4);
  cast_multi<<<dim3(nw / 256, 24), 256, 0, stream>>>(cargs);

  auto gemm = [&](const bf16* A, const bf16* Wt,
                  const float* bb0, const float* bb1, const float* bb2, const float* bb3,
                  bf16* Cp, int M, int N, int Kd, int flags, int nz) {
    gemm_nt<<<dim3(N / 128, M / 128, nz), 256, 0, stream>>>(
        A, Wt, bb0, bb1, bb2, bb3, Cp, M, N, Kd, flags, Kd / nz);
  };

  // 1. merged self-QKV + cross-QV (BK=32 kernel, 1280 blocks = 5/CU exact)
  gemm_qkv<<<dim3(1280), 256, 0, stream>>>(
      x0b, encb, Wqkv_s, Wqv_c, sa_bq, sa_bk, sa_bv, ca_bq, ca_bv,
      Qs, Ks, VTs, Qc, VTc);
  // 2. self attention
  attn_kernel<<<dim3(SEQ / 128, BATCH * NHEAD), 256, 0, stream>>>(Qs, Ks, VTs, ctx);
  // 3. self O-proj split-2 (BK=64 kernel; bf16 partials into dead x0b/encb)
  gemm(ctx, Wo_s, nullptr, nullptr, nullptr, nullptr, pA, NTOK, DMOD, DMOD, 0, 2);
  // 4. LN1(x0 + p + sa_bo)
  add_ln_red<<<dim3(NTOK), 256, 0, stream>>>(x0, pA, pB, nullptr, nullptr, 2,
                                             sa_bo, ln1g, ln1b, out1f, out1b);
  // 5. cross K from out1, split-2 (partials into dead Qs/Ks)
  gemm(out1b, Wk_c, nullptr, nullptr, nullptr, nullptr, pC, NTOK, DMOD, DMOD, 0, 2);
  reduce_cast<<<dim3(NTOK), 256, 0, stream>>>(pC, pD, ca_bk, Kc);
  // 6. cross attention
  attn_kernel<<<dim3(SEQ / 128, BATCH * NHEAD), 256, 0, stream>>>(Qc, Kc, VTc, ctx);
  // 7. cross O-proj split-2
  gemm(ctx, Wo_c, nullptr, nullptr, nullptr, nullptr, pA, NTOK, DMOD, DMOD, 0, 2);
  // 8. LN2 (in-place residual/bf16 reuse)
  add_ln_red<<<dim3(NTOK), 256, 0, stream>>>(out1f, pA, pB, nullptr, nullptr, 2,
                                             ca_bo, ln2g, ln2b, out1f, out1b);
  // 9. FFN1 + ReLU (BK=64 kernel, grid 32x32)
  gemm(out1b, W1b, b1, b1 + 1024, b1 + 2048, b1 + 3072, Hff, NTOK, DFF, DMOD, 1, 1);
  // 10. FFN2 split-4 (BK=64 kernel; partials into dead Qs/Ks/VTs/Qc)
  gemm(Hff, W2b, nullptr, nullptr, nullptr, nullptr, f0, NTOK, DMOD, DFF, 0, 4);
  // 11. LN3 -> d_out (f32)
  add_ln_red<<<dim3(NTOK), 256, 0, stream>>>(out1f, f0, f1, f2, f3, 4,
                                             b2, ln3g, ln3b, (float*)d_out, nullptr);
}